// Round 8
// baseline (191.930 us; speedup 1.0000x reference)
//
#include <hip/hip_runtime.h>

constexpr int HD = 128;      // hidden size
constexpr int BROWS = 64;    // rows per bucket == rows per mega-block
constexpr int CAP = 2048;    // LDS sorted-edge capacity per bucket
constexpr int NBMAX = 2048;  // max buckets (N <= 131072)

typedef __attribute__((ext_vector_type(8))) short short8v;  // 8 bf16 (4 VGPR)
typedef __attribute__((ext_vector_type(4))) float f32x4;
typedef __attribute__((ext_vector_type(2))) float f32x2;

__device__ __forceinline__ int rl(int v, int j) {
    return __builtin_amdgcn_readlane(v, j);
}
__device__ __forceinline__ float rlf(int v, int j) {
    return __uint_as_float((unsigned)__builtin_amdgcn_readlane(v, j));
}
__device__ __forceinline__ unsigned f2bf(float f) {  // f32 -> bf16 bits, RNE
    unsigned u = __float_as_uint(f);
    return (u + 0x7fffu + ((u >> 16) & 1u)) >> 16;
}
__device__ __forceinline__ f32x2 bf2f(unsigned u) {
    f32x2 r = {__uint_as_float(u << 16), __uint_as_float(u & 0xffff0000u)};
    return r;
}

// meta.x layout: bits[31:26] = local row (0..63), bits[25:8] = col*256 (byte
// offset of the xb row; col < 131072 so col*256 < 2^25), bits[7:0] = 0.
#define META_OFF_MASK 0x03FFFF00

// ---------------------------------------------------------------------------
// prep: two block-ranges.
//  [0, PB)     : per-row L1 norm of x; pack xb = bf16x2(x * rnorm)
//  [PB, PB+32) : Wb bf16 pack, B-fragment layout, XOR-swizzled
// ---------------------------------------------------------------------------
__global__ void prep_kernel(const float* __restrict__ x,
                            unsigned* __restrict__ xb,
                            const float* __restrict__ W,
                            unsigned* __restrict__ Wb, int N, int PB) {
    int bid = blockIdx.x;
    int tid = threadIdx.x;
    if (bid < PB) {
        int row = bid * 4 + (tid >> 6);
        int lane = tid & 63;
        if (row >= N) return;
        float2 v = *((const float2*)(x + (size_t)row * HD) + lane);
        float s = fabsf(v.x) + fabsf(v.y);
#pragma unroll
        for (int m = 1; m < 64; m <<= 1) s += __shfl_xor(s, m, 64);
        float rn = 1.0f / fmaxf(s, 1e-12f);
        unsigned lo = f2bf(v.x * rn), hi = f2bf(v.y * rn);
        xb[(size_t)row * 64 + lane] = lo | (hi << 16);
    } else {
        int t = (bid - PB) * 256 + tid;  // 0..8191 => (col, k2)
        int col = t >> 6, k2 = t & 63;
        float w0 = W[col * HD + 2 * k2];
        float w1 = W[col * HD + 2 * k2 + 1];
        unsigned pk = f2bf(w0) | (f2bf(w1) << 16);
        int byte = (col * 256 + k2 * 4) ^ ((col & 7) << 4);
        *(unsigned*)((char*)Wb + byte) = pk;
    }
}

// ---------------------------------------------------------------------------
// hist: LDS-aggregated bucket histogram, int4 edge loads (4096 edges/block).
// ---------------------------------------------------------------------------
__global__ void hist_kernel(const int* __restrict__ rows,
                            int* __restrict__ bcnt, int E, int NB) {
    __shared__ int lbin[NBMAX];
    int tid = threadIdx.x;
    if (NB <= NBMAX) {
        for (int i = tid; i < NBMAX; i += 256) lbin[i] = 0;
        __syncthreads();
        const int4* rows4 = (const int4*)rows;
        int E4 = E >> 2;
        int base4 = blockIdx.x * 1024;
#pragma unroll
        for (int i = 0; i < 4; ++i) {
            int e4 = base4 + i * 256 + tid;
            if (e4 < E4) {
                int4 r = rows4[e4];
                atomicAdd(&lbin[r.x >> 6], 1);
                atomicAdd(&lbin[r.y >> 6], 1);
                atomicAdd(&lbin[r.z >> 6], 1);
                atomicAdd(&lbin[r.w >> 6], 1);
            }
        }
        if (blockIdx.x == 0) {  // scalar tail if E % 4
            for (int e = (E & ~3) + tid; e < E; e += 256)
                atomicAdd(&lbin[rows[e] >> 6], 1);
        }
        __syncthreads();
        for (int i = tid; i < NB; i += 256) {
            int c = lbin[i];
            if (c) atomicAdd(&bcnt[i], c);
        }
    } else {
        int base = blockIdx.x * 4096;
        for (int i = 0; i < 16; ++i) {
            int e = base + i * 256 + tid;
            if (e < E) atomicAdd(&bcnt[rows[e] >> 6], 1);
        }
    }
}

// ---------------------------------------------------------------------------
// bscan: single-block exclusive scan of NB bucket counts (NB <= 2048).
// ---------------------------------------------------------------------------
__global__ void bscan_kernel(const int* __restrict__ bcnt,
                             int* __restrict__ bbase,
                             int* __restrict__ bcursor, int NB) {
    __shared__ int lds[1024];
    int t = threadIdx.x;
    int i0 = 2 * t, i1 = 2 * t + 1;
    int c0 = (i0 < NB) ? bcnt[i0] : 0;
    int c1 = (i1 < NB) ? bcnt[i1] : 0;
    int s = c0 + c1;
    lds[t] = s;
    __syncthreads();
    for (int off = 1; off < 1024; off <<= 1) {
        int add = (t >= off) ? lds[t - off] : 0;
        __syncthreads();
        lds[t] += add;
        __syncthreads();
    }
    int excl = lds[t] - s;
    if (i0 < NB) { bbase[i0] = excl; bcursor[i0] = excl; }
    if (i1 < NB) { bbase[i1] = excl + c0; bcursor[i1] = excl + c0; }
}

// ---------------------------------------------------------------------------
// bscatter: aggregated scatter into bucket-grouped staging (int4 loads,
// nontemporal 8B stores). 512 thr x 8 edges = 4096/block.
// ---------------------------------------------------------------------------
__global__ void __launch_bounds__(512) bscatter_kernel(
    const int* __restrict__ rows, const int* __restrict__ cols,
    const float* __restrict__ vals, int* __restrict__ bcursor,
    int2* __restrict__ bstage, int E, int NB) {
    __shared__ int lbin[NBMAX];
    __shared__ int lbase[NBMAX];
    int tid = threadIdx.x;
    if (NB <= NBMAX) {
        for (int i = tid; i < NBMAX; i += 512) lbin[i] = 0;
        __syncthreads();
        const int4* rows4 = (const int4*)rows;
        const int4* cols4 = (const int4*)cols;
        const float4* vals4 = (const float4*)vals;
        int E4 = E >> 2;
        int base4 = blockIdx.x * 1024;
        int bkt[8], cc[8], vv[8], rk[8];
#pragma unroll
        for (int i = 0; i < 2; ++i) {
            int e4 = base4 + i * 512 + tid;
            bool ok = e4 < E4;
            int4 r4 = ok ? rows4[e4] : make_int4(0, 0, 0, 0);
            int4 c4 = ok ? cols4[e4] : make_int4(0, 0, 0, 0);
            float4 v4 = ok ? vals4[e4] : make_float4(0, 0, 0, 0);
            int ra[4] = {r4.x, r4.y, r4.z, r4.w};
            int ca[4] = {c4.x, c4.y, c4.z, c4.w};
            float va[4] = {v4.x, v4.y, v4.z, v4.w};
#pragma unroll
            for (int k = 0; k < 4; ++k) {
                int ii = i * 4 + k;
                bkt[ii] = -1;
                if (ok) {
                    int r = ra[k];
                    cc[ii] = (ca[k] << 8) | ((r & 63) << 26);
                    vv[ii] = __float_as_int(va[k]);
                    bkt[ii] = r >> 6;
                    rk[ii] = atomicAdd(&lbin[bkt[ii]], 1);
                }
            }
        }
        __syncthreads();
        for (int i = tid; i < NB; i += 512) {
            int c = lbin[i];
            if (c) lbase[i] = atomicAdd(&bcursor[i], c);
        }
        __syncthreads();
#pragma unroll
        for (int i = 0; i < 8; ++i) {
            if (bkt[i] >= 0) {
                long long pk =
                    ((long long)(unsigned)vv[i] << 32) | (unsigned)cc[i];
                __builtin_nontemporal_store(
                    pk, (long long*)&bstage[lbase[bkt[i]] + rk[i]]);
            }
        }
        if (blockIdx.x == 0) {  // scalar tail if E % 4 (direct cursor append)
            for (int e = (E & ~3) + tid; e < E; e += 512) {
                int r = rows[e];
                int p = atomicAdd(&bcursor[r >> 6], 1);
                bstage[p] = make_int2((cols[e] << 8) | ((r & 63) << 26),
                                      __float_as_int(vals[e]));
            }
        }
    } else {
        int base = blockIdx.x * 4096;
        for (int i = 0; i < 8; ++i) {
            int e = base + i * 512 + tid;
            if (e >= E) break;
            int r = rows[e];
            int p = atomicAdd(&bcursor[r >> 6], 1);
            bstage[p] = make_int2((cols[e] << 8) | ((r & 63) << 26),
                                  __float_as_int(vals[e]));
        }
    }
}

// ---------------------------------------------------------------------------
// mega: per 64-row bucket (1024 threads = 16 waves):
//  1. bucket edges -> regs; in-LDS 64-bin counting sort -> local CSR
//  2. gather: 4-row meta prefetch + 8-wide unroll, 4 acc chains (high MLP)
//  3. f -> bf16 -> swizzled LDS A-tile
//  4. GEMM via mfma_f32_16x16x32_bf16 (wave = 16x32 output tile)
//  5. bias, row-L1 via shfl + LDS float atomics, relu, residual, NT store
// ---------------------------------------------------------------------------
__global__ void __launch_bounds__(1024) mega_kernel(
    const float* __restrict__ x, const unsigned* __restrict__ xb,
    int2* bstage, const int* __restrict__ bbase, const int* __restrict__ bcnt,
    const unsigned* __restrict__ Wb, const float* __restrict__ bias,
    const float* __restrict__ tsp, float* __restrict__ out, int N) {
    __shared__ char wb_raw[HD * HD * 2];     // 32 KiB bf16 W, B-layout, swz
    __shared__ char fb_raw[BROWS * HD * 2];  // 16 KiB bf16 F, A-layout, swz
    __shared__ int2 sorted[CAP];             // 16 KiB
    __shared__ int lcnt[BROWS], lbeg[BROWS], lcur[BROWS];
    __shared__ float rowsum[BROWS];

    int tid = threadIdx.x;
    int bid = blockIdx.x;
    int bb = bbase[bid];
    int ct = bcnt[bid];

    if (tid < BROWS) lcnt[tid] = 0;

    // phase 1: bucket edges -> registers
    int2 m0 = make_int2(0, 0), m1 = make_int2(0, 0);
    bool e0 = tid < ct, e1 = tid + 1024 < ct;
    if (e0) m0 = bstage[bb + tid];
    if (e1) m1 = bstage[bb + tid + 1024];
    __syncthreads();

    // phase 2: LDS histogram of local rows
    if (e0) atomicAdd(&lcnt[(unsigned)m0.x >> 26], 1);
    if (e1) atomicAdd(&lcnt[(unsigned)m1.x >> 26], 1);
    __syncthreads();

    // phase 3: wave 0 exclusive-scans the 64 counts
    if (tid < 64) {
        int c = lcnt[tid];
        int s = c;
#pragma unroll
        for (int m = 1; m < 64; m <<= 1) {
            int t2 = __shfl_up(s, m, 64);
            if (tid >= m) s += t2;
        }
        lbeg[tid] = s - c;
        lcur[tid] = s - c;
    }
    __syncthreads();

    // phase 4: scatter edges into LDS-sorted local CSR (+ stage Wb)
    if (e0) {
        int p = atomicAdd(&lcur[(unsigned)m0.x >> 26], 1);
        if (p < CAP) sorted[p] = m0; else bstage[bb + p] = m0;
    }
    if (e1) {
        int p = atomicAdd(&lcur[(unsigned)m1.x >> 26], 1);
        if (p < CAP) sorted[p] = m1; else bstage[bb + p] = m1;
    }
    {
        const float4* s4 = (const float4*)Wb;
        float4* d4 = (float4*)wb_raw;
        for (int i = tid; i < HD * HD * 2 / 16; i += 1024) d4[i] = s4[i];
    }
    __syncthreads();

    int lane = tid & 63;
    int wid = tid >> 6;
    float ts = tsp[0];
    const char* xbl = (const char*)xb + (lane << 2);

    // ---- gather: prefetch all 4 rows' metadata, then 8-wide unroll ----
    int begs[4], cnts[4];
    int2 metas[4];
#pragma unroll
    for (int rr = 0; rr < 4; ++rr) {
        int lr = wid * 4 + rr;
        begs[rr] = lbeg[lr];
        cnts[rr] = lcnt[lr];
        int2 mt = make_int2(0, 0);
        if (lane < cnts[rr]) {
            int pidx = begs[rr] + lane;
            mt = (pidx < CAP) ? sorted[pidx] : bstage[bb + pidx];
        }
        metas[rr] = mt;
    }

    float a0[4], a1[4];
#pragma unroll
    for (int rr = 0; rr < 4; ++rr) {
        int beg = begs[rr], cnt = cnts[rr];
        f32x2 pqA = {0.f, 0.f}, pqB = {0.f, 0.f};
        f32x2 pqC = {0.f, 0.f}, pqD = {0.f, 0.f};
        int2 meta = metas[rr];
        for (int jb = 0; jb < cnt; jb += 64) {
            int rem = cnt - jb;
            if (rem > 64) rem = 64;
            if (jb) {
                meta = make_int2(0, 0);
                if (lane < rem) {
                    int pidx = beg + jb + lane;
                    meta = (pidx < CAP) ? sorted[pidx] : bstage[bb + pidx];
                }
            }
            int j = 0;
            for (; j + 8 <= rem; j += 8) {
                int o0 = rl(meta.x, j) & META_OFF_MASK;
                int o1 = rl(meta.x, j + 1) & META_OFF_MASK;
                int o2 = rl(meta.x, j + 2) & META_OFF_MASK;
                int o3 = rl(meta.x, j + 3) & META_OFF_MASK;
                int o4 = rl(meta.x, j + 4) & META_OFF_MASK;
                int o5 = rl(meta.x, j + 5) & META_OFF_MASK;
                int o6 = rl(meta.x, j + 6) & META_OFF_MASK;
                int o7 = rl(meta.x, j + 7) & META_OFF_MASK;
                float s0 = rlf(meta.y, j), s1 = rlf(meta.y, j + 1);
                float s2 = rlf(meta.y, j + 2), s3 = rlf(meta.y, j + 3);
                float s4 = rlf(meta.y, j + 4), s5 = rlf(meta.y, j + 5);
                float s6 = rlf(meta.y, j + 6), s7 = rlf(meta.y, j + 7);
                unsigned u0 = *(const unsigned*)(xbl + o0);
                unsigned u1 = *(const unsigned*)(xbl + o1);
                unsigned u2 = *(const unsigned*)(xbl + o2);
                unsigned u3 = *(const unsigned*)(xbl + o3);
                unsigned u4 = *(const unsigned*)(xbl + o4);
                unsigned u5 = *(const unsigned*)(xbl + o5);
                unsigned u6 = *(const unsigned*)(xbl + o6);
                unsigned u7 = *(const unsigned*)(xbl + o7);
                pqA += bf2f(u0) * s0;
                pqB += bf2f(u1) * s1;
                pqC += bf2f(u2) * s2;
                pqD += bf2f(u3) * s3;
                pqA += bf2f(u4) * s4;
                pqB += bf2f(u5) * s5;
                pqC += bf2f(u6) * s6;
                pqD += bf2f(u7) * s7;
            }
            for (; j < rem; ++j) {
                int o0 = rl(meta.x, j) & META_OFF_MASK;
                float s0 = rlf(meta.y, j);
                unsigned u0 = *(const unsigned*)(xbl + o0);
                pqA += bf2f(u0) * s0;
            }
        }
        f32x2 t = pqA + pqB + pqC + pqD;
        a0[rr] = t.x;
        a1[rr] = t.y;
    }

    // ---- phase C: f -> bf16 swizzled LDS A-tile; init rowsum ----
#pragma unroll
    for (int rr = 0; rr < 4; ++rr) {
        int row = wid * 4 + rr;  // local row
        unsigned pk = f2bf(a0[rr]) | (f2bf(a1[rr]) << 16);
        int byte = (row * 256 + lane * 4) ^ ((row & 7) << 4);
        *(unsigned*)(fb_raw + byte) = pk;
    }
    if (tid < BROWS) rowsum[tid] = 0.f;
    __syncthreads();

    // ---- MFMA GEMM: wave -> 16-row x 32-col output tile ----
    int rt = wid >> 2;        // row-tile 0..3
    int ct0 = (wid & 3) * 2;  // first col-tile (of 8)
    int c = lane & 15;
    int kg = lane >> 4;
    int arow = rt * 16 + c;
    int bcol0 = ct0 * 16 + c;
    int bcol1 = bcol0 + 16;
    f32x4 acc0 = {0.f, 0.f, 0.f, 0.f}, acc1 = {0.f, 0.f, 0.f, 0.f};
#pragma unroll
    for (int kk = 0; kk < 4; ++kk) {
        int ka = kg * 16 + kk * 64;  // byte offset of this lane's k-chunk
        short8v af = *(const short8v*)(fb_raw +
                                       ((arow * 256 + ka) ^ ((arow & 7) << 4)));
        short8v bf0 = *(const short8v*)(wb_raw +
                                        ((bcol0 * 256 + ka) ^ ((bcol0 & 7) << 4)));
        short8v bf1 = *(const short8v*)(wb_raw +
                                        ((bcol1 * 256 + ka) ^ ((bcol1 & 7) << 4)));
        acc0 = __builtin_amdgcn_mfma_f32_16x16x32_bf16(af, bf0, acc0, 0, 0, 0);
        acc1 = __builtin_amdgcn_mfma_f32_16x16x32_bf16(af, bf1, acc1, 0, 0, 0);
    }

    // ---- epilogue: bias, row-L1 reduce, normalize, relu, residual ----
    float bias0 = bias[bcol0];
    float bias1 = bias[bcol1];
    float g0r[4], g1r[4];
#pragma unroll
    for (int r = 0; r < 4; ++r) {
        float v0 = acc0[r] + bias0;
        float v1 = acc1[r] + bias1;
        g0r[r] = v0;
        g1r[r] = v1;
        float s = fabsf(v0) + fabsf(v1);
        s += __shfl_xor(s, 1, 64);
        s += __shfl_xor(s, 2, 64);
        s += __shfl_xor(s, 4, 64);
        s += __shfl_xor(s, 8, 64);
        if (c == 0) atomicAdd(&rowsum[rt * 16 + kg * 4 + r], s);
    }
    __syncthreads();
#pragma unroll
    for (int r = 0; r < 4; ++r) {
        int lrow = rt * 16 + kg * 4 + r;
        int row = bid * BROWS + lrow;
        if (row < N) {
            float rn = 1.0f / fmaxf(rowsum[lrow], 1e-12f);
            float G0 = fmaxf(g0r[r] * rn, 0.f);
            float G1 = fmaxf(g1r[r] * rn, 0.f);
            float x0 = __builtin_nontemporal_load(&x[(size_t)row * HD + bcol0]);
            float x1 = __builtin_nontemporal_load(&x[(size_t)row * HD + bcol1]);
            __builtin_nontemporal_store(fmaf(ts, G0, x0),
                                        &out[(size_t)row * HD + bcol0]);
            __builtin_nontemporal_store(fmaf(ts, G1, x1),
                                        &out[(size_t)row * HD + bcol1]);
        }
    }
}

extern "C" void kernel_launch(void* const* d_in, const int* in_sizes, int n_in,
                              void* d_out, int out_size, void* d_ws,
                              size_t ws_size, hipStream_t stream) {
    const float* x = (const float*)d_in[0];
    const int* Ar = (const int*)d_in[1];
    const int* Ac = (const int*)d_in[2];
    const float* Av = (const float*)d_in[3];
    const float* W = (const float*)d_in[4];
    const float* b = (const float*)d_in[5];
    const float* ts = (const float*)d_in[6];

    int N = in_sizes[0] / HD;
    int E = in_sizes[1];
    float* out = (float*)d_out;

    int NB = (N + BROWS - 1) / BROWS;

    char* ws = (char*)d_ws;
    size_t o = 0;
    auto take = [&](size_t bytes) {
        void* p = ws + o;
        o += (bytes + 511) & ~(size_t)511;
        return p;
    };
    int* bcnt = (int*)take((size_t)NB * 4);
    int* bbase = (int*)take((size_t)NB * 4);
    int* bcursor = (int*)take((size_t)NB * 4);
    unsigned* Wb = (unsigned*)take((size_t)HD * HD * 2);
    unsigned* xb = (unsigned*)take((size_t)N * 64 * 4);
    int2* bstage = (int2*)take((size_t)E * 8);

    hipMemsetAsync(bcnt, 0, (size_t)NB * 4, stream);

    int PB = (N + 3) / 4;
    int HB = (E + 4095) / 4096;
    prep_kernel<<<PB + 32, 256, 0, stream>>>(x, xb, W, Wb, N, PB);
    hist_kernel<<<HB, 256, 0, stream>>>(Ar, bcnt, E, NB);
    bscan_kernel<<<1, 1024, 0, stream>>>(bcnt, bbase, bcursor, NB);
    bscatter_kernel<<<HB, 512, 0, stream>>>(Ar, Ac, Av, bcursor, bstage, E, NB);
    mega_kernel<<<NB, 1024, 0, stream>>>(x, xb, bstage, bbase, bcnt, Wb, b, ts,
                                         out, N);
}

// Round 9
// 161.714 us; speedup vs baseline: 1.1868x; 1.1868x over previous
//
#include <hip/hip_runtime.h>

constexpr int HD = 128;      // hidden size
constexpr int BROWS = 64;    // rows per bucket == rows per mega-block
constexpr int CAP = 2048;    // LDS sorted-edge capacity per bucket
constexpr int NBMAX = 2048;  // max buckets (N <= 131072)

typedef __attribute__((ext_vector_type(8))) short short8v;  // 8 bf16 (4 VGPR)
typedef __attribute__((ext_vector_type(4))) float f32x4;
typedef __attribute__((ext_vector_type(2))) float f32x2;

__device__ __forceinline__ int rl(int v, int j) {
    return __builtin_amdgcn_readlane(v, j);
}
__device__ __forceinline__ float rlf(int v, int j) {
    return __uint_as_float((unsigned)__builtin_amdgcn_readlane(v, j));
}
__device__ __forceinline__ unsigned f2bf(float f) {  // f32 -> bf16 bits, RNE
    unsigned u = __float_as_uint(f);
    return (u + 0x7fffu + ((u >> 16) & 1u)) >> 16;
}
__device__ __forceinline__ f32x2 bf2f(unsigned u) {
    f32x2 r = {__uint_as_float(u << 16), __uint_as_float(u & 0xffff0000u)};
    return r;
}

// meta.x layout: bits[31:26] = local row (0..63), bits[25:8] = col*256 (byte
// offset of the xb row; col < 131072 so col*256 < 2^25), bits[7:0] = 0.
#define META_OFF_MASK 0x03FFFF00

// ---------------------------------------------------------------------------
// prep: two block-ranges.
//  [0, PB)     : per-row L1 norm of x; pack xb = bf16x2(x * rnorm);
//                store xnorm[row] = max(L1,1e-12) for residual reconstruction
//  [PB, PB+32) : Wb bf16 pack, B-fragment layout, XOR-swizzled
// ---------------------------------------------------------------------------
__global__ void prep_kernel(const float* __restrict__ x,
                            unsigned* __restrict__ xb,
                            float* __restrict__ xnorm,
                            const float* __restrict__ W,
                            unsigned* __restrict__ Wb, int N, int PB) {
    int bid = blockIdx.x;
    int tid = threadIdx.x;
    if (bid < PB) {
        int row = bid * 4 + (tid >> 6);
        int lane = tid & 63;
        if (row >= N) return;
        float2 v = *((const float2*)(x + (size_t)row * HD) + lane);
        float s = fabsf(v.x) + fabsf(v.y);
#pragma unroll
        for (int m = 1; m < 64; m <<= 1) s += __shfl_xor(s, m, 64);
        float nm = fmaxf(s, 1e-12f);
        float rn = 1.0f / nm;
        if (lane == 0) xnorm[row] = nm;
        unsigned lo = f2bf(v.x * rn), hi = f2bf(v.y * rn);
        xb[(size_t)row * 64 + lane] = lo | (hi << 16);
    } else {
        int t = (bid - PB) * 256 + tid;  // 0..8191 => (col, k2)
        int col = t >> 6, k2 = t & 63;
        float w0 = W[col * HD + 2 * k2];
        float w1 = W[col * HD + 2 * k2 + 1];
        unsigned pk = f2bf(w0) | (f2bf(w1) << 16);
        int byte = (col * 256 + k2 * 4) ^ ((col & 7) << 4);
        *(unsigned*)((char*)Wb + byte) = pk;
    }
}

// ---------------------------------------------------------------------------
// hist: LDS-aggregated bucket histogram. 256 thr x 16 edges = 4096/block.
// ---------------------------------------------------------------------------
__global__ void hist_kernel(const int* __restrict__ rows,
                            int* __restrict__ bcnt, int E, int NB) {
    __shared__ int lbin[NBMAX];
    if (NB <= NBMAX) {
        for (int i = threadIdx.x; i < NBMAX; i += 256) lbin[i] = 0;
        __syncthreads();
        int base = blockIdx.x * 4096;
#pragma unroll 4
        for (int i = 0; i < 16; ++i) {
            int e = base + i * 256 + threadIdx.x;
            if (e < E) atomicAdd(&lbin[rows[e] >> 6], 1);
        }
        __syncthreads();
        for (int i = threadIdx.x; i < NB; i += 256) {
            int c = lbin[i];
            if (c) atomicAdd(&bcnt[i], c);
        }
    } else {
        int base = blockIdx.x * 4096;
        for (int i = 0; i < 16; ++i) {
            int e = base + i * 256 + threadIdx.x;
            if (e < E) atomicAdd(&bcnt[rows[e] >> 6], 1);
        }
    }
}

// ---------------------------------------------------------------------------
// bscan: single-block exclusive scan of NB bucket counts (NB <= 2048).
// ---------------------------------------------------------------------------
__global__ void bscan_kernel(const int* __restrict__ bcnt,
                             int* __restrict__ bbase,
                             int* __restrict__ bcursor, int NB) {
    __shared__ int lds[1024];
    int t = threadIdx.x;
    int i0 = 2 * t, i1 = 2 * t + 1;
    int c0 = (i0 < NB) ? bcnt[i0] : 0;
    int c1 = (i1 < NB) ? bcnt[i1] : 0;
    int s = c0 + c1;
    lds[t] = s;
    __syncthreads();
    for (int off = 1; off < 1024; off <<= 1) {
        int add = (t >= off) ? lds[t - off] : 0;
        __syncthreads();
        lds[t] += add;
        __syncthreads();
    }
    int excl = lds[t] - s;
    if (i0 < NB) { bbase[i0] = excl; bcursor[i0] = excl; }
    if (i1 < NB) { bbase[i1] = excl + c0; bcursor[i1] = excl + c0; }
}

// ---------------------------------------------------------------------------
// bscatter: aggregated scatter into bucket-grouped staging.
// Per block: LDS-rank each edge within its bucket, reserve a contiguous
// global range per nonzero bucket (ONE global atomic each), write
// bstage[base+rank] = {packed meta, val}.
// ---------------------------------------------------------------------------
__global__ void __launch_bounds__(512) bscatter_kernel(
    const int* __restrict__ rows, const int* __restrict__ cols,
    const float* __restrict__ vals, int* __restrict__ bcursor,
    int2* __restrict__ bstage, int E, int NB) {
    __shared__ int lbin[NBMAX];
    __shared__ int lbase[NBMAX];
    int tid = threadIdx.x;
    int base = blockIdx.x * 4096;
    if (NB <= NBMAX) {
        for (int i = tid; i < NBMAX; i += 512) lbin[i] = 0;
        __syncthreads();
        int bkt[8], cc[8], vv[8], rk[8];
#pragma unroll
        for (int i = 0; i < 8; ++i) {
            int e = base + i * 512 + tid;
            bkt[i] = -1;
            if (e < E) {
                int r = rows[e];
                cc[i] = (cols[e] << 8) | ((r & 63) << 26);
                vv[i] = __float_as_int(vals[e]);
                bkt[i] = r >> 6;
                rk[i] = atomicAdd(&lbin[bkt[i]], 1);
            }
        }
        __syncthreads();
        for (int i = tid; i < NB; i += 512) {
            int c = lbin[i];
            if (c) lbase[i] = atomicAdd(&bcursor[i], c);
        }
        __syncthreads();
#pragma unroll
        for (int i = 0; i < 8; ++i) {
            if (bkt[i] >= 0)
                bstage[lbase[bkt[i]] + rk[i]] = make_int2(cc[i], vv[i]);
        }
    } else {
        for (int i = 0; i < 8; ++i) {
            int e = base + i * 512 + tid;
            if (e >= E) break;
            int r = rows[e];
            int p = atomicAdd(&bcursor[r >> 6], 1);
            bstage[p] = make_int2((cols[e] << 8) | ((r & 63) << 26),
                                  __float_as_int(vals[e]));
        }
    }
}

// ---------------------------------------------------------------------------
// mega: per 64-row bucket (1024 threads = 16 waves):
//  1. bucket edges -> regs; in-LDS 64-bin counting sort -> local CSR
//  2. gather: each wave accumulates 4 f-rows (f32x2 FMA, 4-wide unroll)
//  3. f -> bf16 -> swizzled LDS A-tile
//  4. GEMM via mfma_f32_16x16x32_bf16 (wave = 16x32 output tile)
//  5. bias, row-L1 via shfl + LDS float atomics, relu, residual
//     (residual reconstructed from xb * xnorm -- no x re-read), store
// ---------------------------------------------------------------------------
__global__ void __launch_bounds__(1024) mega_kernel(
    const unsigned* __restrict__ xb, const float* __restrict__ xnorm,
    int2* bstage, const int* __restrict__ bbase, const int* __restrict__ bcnt,
    const unsigned* __restrict__ Wb, const float* __restrict__ bias,
    const float* __restrict__ tsp, float* __restrict__ out, int N) {
    __shared__ char wb_raw[HD * HD * 2];     // 32 KiB bf16 W, B-layout, swz
    __shared__ char fb_raw[BROWS * HD * 2];  // 16 KiB bf16 F, A-layout, swz
    __shared__ int2 sorted[CAP];             // 16 KiB
    __shared__ int lcnt[BROWS], lbeg[BROWS], lcur[BROWS];
    __shared__ float rowsum[BROWS];

    int tid = threadIdx.x;
    int bid = blockIdx.x;
    int bb = bbase[bid];
    int ct = bcnt[bid];

    if (tid < BROWS) lcnt[tid] = 0;

    // phase 1: bucket edges -> registers
    int2 m0 = make_int2(0, 0), m1 = make_int2(0, 0);
    bool e0 = tid < ct, e1 = tid + 1024 < ct;
    if (e0) m0 = bstage[bb + tid];
    if (e1) m1 = bstage[bb + tid + 1024];
    __syncthreads();

    // phase 2: LDS histogram of local rows
    if (e0) atomicAdd(&lcnt[(unsigned)m0.x >> 26], 1);
    if (e1) atomicAdd(&lcnt[(unsigned)m1.x >> 26], 1);
    __syncthreads();

    // phase 3: wave 0 exclusive-scans the 64 counts
    if (tid < 64) {
        int c = lcnt[tid];
        int s = c;
#pragma unroll
        for (int m = 1; m < 64; m <<= 1) {
            int t2 = __shfl_up(s, m, 64);
            if (tid >= m) s += t2;
        }
        lbeg[tid] = s - c;
        lcur[tid] = s - c;
    }
    __syncthreads();

    // phase 4: scatter edges into LDS-sorted local CSR (+ stage Wb)
    if (e0) {
        int p = atomicAdd(&lcur[(unsigned)m0.x >> 26], 1);
        if (p < CAP) sorted[p] = m0; else bstage[bb + p] = m0;
    }
    if (e1) {
        int p = atomicAdd(&lcur[(unsigned)m1.x >> 26], 1);
        if (p < CAP) sorted[p] = m1; else bstage[bb + p] = m1;
    }
    {
        const float4* s4 = (const float4*)Wb;
        float4* d4 = (float4*)wb_raw;
        for (int i = tid; i < HD * HD * 2 / 16; i += 1024) d4[i] = s4[i];
    }
    __syncthreads();

    int lane = tid & 63;
    int wid = tid >> 6;
    float ts = tsp[0];
    const char* xbl = (const char*)xb + (lane << 2);

    // ---- gather: accumulate 4 f-rows (f32x2) per wave ----
    float a0[4], a1[4];
#pragma unroll
    for (int rr = 0; rr < 4; ++rr) {
        int lr = wid * 4 + rr;
        int beg = lbeg[lr], cnt = lcnt[lr];
        f32x2 pq0 = {0.f, 0.f}, pq1 = {0.f, 0.f};
        for (int jb = 0; jb < cnt; jb += 64) {
            int rem = cnt - jb;
            if (rem > 64) rem = 64;
            int2 meta = make_int2(0, 0);
            if (lane < rem) {
                int pidx = beg + jb + lane;
                meta = (pidx < CAP) ? sorted[pidx] : bstage[bb + pidx];
            }
            int j = 0;
            for (; j + 4 <= rem; j += 4) {
                int o0 = rl(meta.x, j) & META_OFF_MASK;
                int o1 = rl(meta.x, j + 1) & META_OFF_MASK;
                int o2 = rl(meta.x, j + 2) & META_OFF_MASK;
                int o3 = rl(meta.x, j + 3) & META_OFF_MASK;
                float s0 = rlf(meta.y, j), s1 = rlf(meta.y, j + 1);
                float s2 = rlf(meta.y, j + 2), s3 = rlf(meta.y, j + 3);
                unsigned u0 = *(const unsigned*)(xbl + o0);
                unsigned u1 = *(const unsigned*)(xbl + o1);
                unsigned u2 = *(const unsigned*)(xbl + o2);
                unsigned u3 = *(const unsigned*)(xbl + o3);
                pq0 += bf2f(u0) * s0;
                pq1 += bf2f(u1) * s1;
                pq0 += bf2f(u2) * s2;
                pq1 += bf2f(u3) * s3;
            }
            for (; j < rem; ++j) {
                int o0 = rl(meta.x, j) & META_OFF_MASK;
                float s0 = rlf(meta.y, j);
                unsigned u0 = *(const unsigned*)(xbl + o0);
                pq0 += bf2f(u0) * s0;
            }
        }
        a0[rr] = pq0.x + pq1.x;
        a1[rr] = pq0.y + pq1.y;
    }

    // ---- phase C: f -> bf16 swizzled LDS A-tile; init rowsum ----
#pragma unroll
    for (int rr = 0; rr < 4; ++rr) {
        int row = wid * 4 + rr;  // local row
        unsigned pk = f2bf(a0[rr]) | (f2bf(a1[rr]) << 16);
        int byte = (row * 256 + lane * 4) ^ ((row & 7) << 4);
        *(unsigned*)(fb_raw + byte) = pk;
    }
    if (tid < BROWS) rowsum[tid] = 0.f;
    __syncthreads();

    // ---- MFMA GEMM: wave -> 16-row x 32-col output tile ----
    int rt = wid >> 2;        // row-tile 0..3
    int ct0 = (wid & 3) * 2;  // first col-tile (of 8)
    int c = lane & 15;
    int kg = lane >> 4;
    int arow = rt * 16 + c;
    int bcol0 = ct0 * 16 + c;
    int bcol1 = bcol0 + 16;
    f32x4 acc0 = {0.f, 0.f, 0.f, 0.f}, acc1 = {0.f, 0.f, 0.f, 0.f};
#pragma unroll
    for (int kk = 0; kk < 4; ++kk) {
        int ka = kg * 16 + kk * 64;  // byte offset of this lane's k-chunk
        short8v af = *(const short8v*)(fb_raw +
                                       ((arow * 256 + ka) ^ ((arow & 7) << 4)));
        short8v bf0 = *(const short8v*)(wb_raw +
                                        ((bcol0 * 256 + ka) ^ ((bcol0 & 7) << 4)));
        short8v bf1 = *(const short8v*)(wb_raw +
                                        ((bcol1 * 256 + ka) ^ ((bcol1 & 7) << 4)));
        acc0 = __builtin_amdgcn_mfma_f32_16x16x32_bf16(af, bf0, acc0, 0, 0, 0);
        acc1 = __builtin_amdgcn_mfma_f32_16x16x32_bf16(af, bf1, acc1, 0, 0, 0);
    }

    // ---- epilogue: bias, row-L1 reduce, normalize, relu, residual ----
    float bias0 = bias[bcol0];
    float bias1 = bias[bcol1];
    float g0r[4], g1r[4];
#pragma unroll
    for (int r = 0; r < 4; ++r) {
        float v0 = acc0[r] + bias0;
        float v1 = acc1[r] + bias1;
        g0r[r] = v0;
        g1r[r] = v1;
        float s = fabsf(v0) + fabsf(v1);
        s += __shfl_xor(s, 1, 64);
        s += __shfl_xor(s, 2, 64);
        s += __shfl_xor(s, 4, 64);
        s += __shfl_xor(s, 8, 64);
        if (c == 0) atomicAdd(&rowsum[rt * 16 + kg * 4 + r], s);
    }
    __syncthreads();
#pragma unroll
    for (int r = 0; r < 4; ++r) {
        int lrow = rt * 16 + kg * 4 + r;
        int row = bid * BROWS + lrow;
        if (row < N) {
            float rn = 1.0f / fmaxf(rowsum[lrow], 1e-12f);
            float G0 = fmaxf(g0r[r] * rn, 0.f);
            float G1 = fmaxf(g1r[r] * rn, 0.f);
            // residual reconstruction: x = bf16(x * (1/norm)) * norm
            float nm = xnorm[row];
            unsigned u0 = xb[(size_t)row * 64 + ct0 * 8 + (c >> 1)];
            unsigned u1 = xb[(size_t)row * 64 + ct0 * 8 + 8 + (c >> 1)];
            unsigned h0 = (c & 1) ? (u0 & 0xffff0000u) : (u0 << 16);
            unsigned h1 = (c & 1) ? (u1 & 0xffff0000u) : (u1 << 16);
            float x0 = __uint_as_float(h0) * nm;
            float x1 = __uint_as_float(h1) * nm;
            out[(size_t)row * HD + bcol0] = fmaf(ts, G0, x0);
            out[(size_t)row * HD + bcol1] = fmaf(ts, G1, x1);
        }
    }
}

extern "C" void kernel_launch(void* const* d_in, const int* in_sizes, int n_in,
                              void* d_out, int out_size, void* d_ws,
                              size_t ws_size, hipStream_t stream) {
    const float* x = (const float*)d_in[0];
    const int* Ar = (const int*)d_in[1];
    const int* Ac = (const int*)d_in[2];
    const float* Av = (const float*)d_in[3];
    const float* W = (const float*)d_in[4];
    const float* b = (const float*)d_in[5];
    const float* ts = (const float*)d_in[6];

    int N = in_sizes[0] / HD;
    int E = in_sizes[1];
    float* out = (float*)d_out;

    int NB = (N + BROWS - 1) / BROWS;

    char* ws = (char*)d_ws;
    size_t o = 0;
    auto take = [&](size_t bytes) {
        void* p = ws + o;
        o += (bytes + 511) & ~(size_t)511;
        return p;
    };
    int* bcnt = (int*)take((size_t)NB * 4);
    int* bbase = (int*)take((size_t)NB * 4);
    int* bcursor = (int*)take((size_t)NB * 4);
    float* xnorm = (float*)take((size_t)N * 4);
    unsigned* Wb = (unsigned*)take((size_t)HD * HD * 2);
    unsigned* xb = (unsigned*)take((size_t)N * 64 * 4);
    int2* bstage = (int2*)take((size_t)E * 8);

    hipMemsetAsync(bcnt, 0, (size_t)NB * 4, stream);

    int PB = (N + 3) / 4;
    int HB = (E + 4095) / 4096;
    prep_kernel<<<PB + 32, 256, 0, stream>>>(x, xb, xnorm, W, Wb, N, PB);
    hist_kernel<<<HB, 256, 0, stream>>>(Ar, bcnt, E, NB);
    bscan_kernel<<<1, 1024, 0, stream>>>(bcnt, bbase, bcursor, NB);
    bscatter_kernel<<<HB, 512, 0, stream>>>(Ar, Ac, Av, bcursor, bstage, E, NB);
    mega_kernel<<<NB, 1024, 0, stream>>>(xb, xnorm, bstage, bbase, bcnt, Wb, b,
                                         ts, out, N);
}

// Round 10
// 140.813 us; speedup vs baseline: 1.3630x; 1.1484x over previous
//
#include <hip/hip_runtime.h>

constexpr int HD = 128;      // hidden size
constexpr int BROWS = 64;    // rows per bucket == rows per mega-block
constexpr int CAP = 2048;    // LDS sorted-edge capacity per bucket
constexpr int NBMAX = 2048;  // max buckets (N <= 131072)
constexpr int EPB = 16384;   // edges per count/scatter block

typedef __attribute__((ext_vector_type(8))) short short8v;  // 8 bf16 (4 VGPR)
typedef __attribute__((ext_vector_type(4))) float f32x4;
typedef __attribute__((ext_vector_type(2))) float f32x2;

__device__ __forceinline__ int rl(int v, int j) {
    return __builtin_amdgcn_readlane(v, j);
}
__device__ __forceinline__ float rlf(int v, int j) {
    return __uint_as_float((unsigned)__builtin_amdgcn_readlane(v, j));
}
__device__ __forceinline__ unsigned f2bf(float f) {  // f32 -> bf16 bits, RNE
    unsigned u = __float_as_uint(f);
    return (u + 0x7fffu + ((u >> 16) & 1u)) >> 16;
}
__device__ __forceinline__ f32x2 bf2f(unsigned u) {
    f32x2 r = {__uint_as_float(u << 16), __uint_as_float(u & 0xffff0000u)};
    return r;
}

// meta.x layout: bits[31:26] = local row (0..63), bits[25:8] = col*256 (byte
// offset of the xb row; col < 131072 so col*256 < 2^25), bits[7:0] = 0.
#define META_OFF_MASK 0x03FFFF00

// ---------------------------------------------------------------------------
// prep: three block-ranges.
//  [0, PB)       : per-row L1 norm of x; pack xb = bf16x2(x*rnorm); xnorm
//  [PB, PB+32)   : Wb bf16 pack, B-fragment layout, XOR-swizzled
//  [PB+32, +1)   : zero bcnt (replaces hipMemsetAsync dispatch)
// ---------------------------------------------------------------------------
__global__ void prep_kernel(const float* __restrict__ x,
                            unsigned* __restrict__ xb,
                            float* __restrict__ xnorm,
                            const float* __restrict__ W,
                            unsigned* __restrict__ Wb,
                            int* __restrict__ bcnt,
                            int N, int PB, int NB) {
    int bid = blockIdx.x;
    int tid = threadIdx.x;
    if (bid < PB) {
        int row = bid * 4 + (tid >> 6);
        int lane = tid & 63;
        if (row >= N) return;
        float2 v = *((const float2*)(x + (size_t)row * HD) + lane);
        float s = fabsf(v.x) + fabsf(v.y);
#pragma unroll
        for (int m = 1; m < 64; m <<= 1) s += __shfl_xor(s, m, 64);
        float nm = fmaxf(s, 1e-12f);
        float rn = 1.0f / nm;
        if (lane == 0) xnorm[row] = nm;
        unsigned lo = f2bf(v.x * rn), hi = f2bf(v.y * rn);
        xb[(size_t)row * 64 + lane] = lo | (hi << 16);
    } else if (bid < PB + 32) {
        int t = (bid - PB) * 256 + tid;  // 0..8191 => (col, k2)
        int col = t >> 6, k2 = t & 63;
        float w0 = W[col * HD + 2 * k2];
        float w1 = W[col * HD + 2 * k2 + 1];
        unsigned pk = f2bf(w0) | (f2bf(w1) << 16);
        int byte = (col * 256 + k2 * 4) ^ ((col & 7) << 4);
        *(unsigned*)((char*)Wb + byte) = pk;
    } else {
        for (int i = tid; i < NB; i += 256) bcnt[i] = 0;
    }
}

// ---------------------------------------------------------------------------
// count: LDS-aggregated bucket histogram, 512 thr x 32 edges = 16384/block.
// Global flush: one atomicAdd per (block, nonzero bin) -> ~143K atomics.
// ---------------------------------------------------------------------------
__global__ void __launch_bounds__(512) count_kernel(
    const int* __restrict__ rows, int* __restrict__ bcnt, int E, int NB) {
    int tid = threadIdx.x;
    if (NB <= NBMAX) {
        __shared__ int lbin[NBMAX];
        for (int i = tid; i < NBMAX; i += 512) lbin[i] = 0;
        __syncthreads();
        const int4* rows4 = (const int4*)rows;
        int E4 = E >> 2;
        int base4 = blockIdx.x * (EPB / 4);
#pragma unroll
        for (int i = 0; i < 8; ++i) {
            int e4 = base4 + i * 512 + tid;
            if (e4 < E4) {
                int4 r = rows4[e4];
                atomicAdd(&lbin[r.x >> 6], 1);
                atomicAdd(&lbin[r.y >> 6], 1);
                atomicAdd(&lbin[r.z >> 6], 1);
                atomicAdd(&lbin[r.w >> 6], 1);
            }
        }
        if (blockIdx.x == 0) {  // scalar tail (E % 4)
            for (int e = (E & ~3) + tid; e < E; e += 512)
                atomicAdd(&lbin[rows[e] >> 6], 1);
        }
        __syncthreads();
        for (int i = tid; i < NB; i += 512) {
            int c = lbin[i];
            if (c) atomicAdd(&bcnt[i], c);
        }
    } else {  // fallback: direct atomics
        int base = blockIdx.x * EPB;
        for (int i = 0; i < 32; ++i) {
            int e = base + i * 512 + tid;
            if (e < E) atomicAdd(&bcnt[rows[e] >> 6], 1);
        }
    }
}

// ---------------------------------------------------------------------------
// bscan: single-block exclusive scan of NB bucket counts (NB <= 2048).
// ---------------------------------------------------------------------------
__global__ void bscan_kernel(const int* __restrict__ bcnt,
                             int* __restrict__ bbase,
                             int* __restrict__ bcursor, int NB) {
    __shared__ int lds[1024];
    int t = threadIdx.x;
    int i0 = 2 * t, i1 = 2 * t + 1;
    int c0 = (i0 < NB) ? bcnt[i0] : 0;
    int c1 = (i1 < NB) ? bcnt[i1] : 0;
    int s = c0 + c1;
    lds[t] = s;
    __syncthreads();
    for (int off = 1; off < 1024; off <<= 1) {
        int add = (t >= off) ? lds[t - off] : 0;
        __syncthreads();
        lds[t] += add;
        __syncthreads();
    }
    int excl = lds[t] - s;
    if (i0 < NB) { bbase[i0] = excl; bcursor[i0] = excl; }
    if (i1 < NB) { bbase[i1] = excl + c0; bcursor[i1] = excl + c0; }
}

// ---------------------------------------------------------------------------
// scatter: two-pass ranked scatter, 512 thr x 32 edges = 16384/block.
// Pass A: per-edge local rank via LDS atomics (ranks -> u16 LDS array).
// Reserve: ONE global atomicAdd per (block, nonzero bucket) -> contiguous
// range; ~10.5 edges/bucket/block then write back-to-back (dense lines).
// Pass B: re-read edges (L2-hot), write bstage[base+rank].
// ---------------------------------------------------------------------------
__global__ void __launch_bounds__(512) scatter_kernel(
    const int* __restrict__ rows, const int* __restrict__ cols,
    const float* __restrict__ vals, int* __restrict__ bcursor,
    int2* __restrict__ bstage, int E, int NB) {
    int tid = threadIdx.x;
    if (NB <= NBMAX) {
        __shared__ int lbin[NBMAX];
        __shared__ int lbase[NBMAX];
        __shared__ unsigned short rk16[EPB];
        for (int i = tid; i < NBMAX; i += 512) lbin[i] = 0;
        __syncthreads();
        const int4* rows4 = (const int4*)rows;
        int E4 = E >> 2;
        int base4 = blockIdx.x * (EPB / 4);
        // pass A: local ranks
#pragma unroll
        for (int i = 0; i < 8; ++i) {
            int e4 = base4 + i * 512 + tid;
            if (e4 < E4) {
                int4 r = rows4[e4];
                int li = (i * 512 + tid) * 4;
                rk16[li + 0] = (unsigned short)atomicAdd(&lbin[r.x >> 6], 1);
                rk16[li + 1] = (unsigned short)atomicAdd(&lbin[r.y >> 6], 1);
                rk16[li + 2] = (unsigned short)atomicAdd(&lbin[r.z >> 6], 1);
                rk16[li + 3] = (unsigned short)atomicAdd(&lbin[r.w >> 6], 1);
            }
        }
        __syncthreads();
        // reserve contiguous global ranges
        for (int i = tid; i < NB; i += 512) {
            int c = lbin[i];
            if (c) lbase[i] = atomicAdd(&bcursor[i], c);
        }
        __syncthreads();
        // pass B: write edges to reserved slots
        const int4* cols4 = (const int4*)cols;
        const float4* vals4 = (const float4*)vals;
#pragma unroll
        for (int i = 0; i < 8; ++i) {
            int e4 = base4 + i * 512 + tid;
            if (e4 < E4) {
                int4 r4 = rows4[e4];
                int4 c4 = cols4[e4];
                float4 v4 = vals4[e4];
                int li = (i * 512 + tid) * 4;
                int ra[4] = {r4.x, r4.y, r4.z, r4.w};
                int ca[4] = {c4.x, c4.y, c4.z, c4.w};
                float va[4] = {v4.x, v4.y, v4.z, v4.w};
#pragma unroll
                for (int k = 0; k < 4; ++k) {
                    int r = ra[k];
                    int slot = lbase[r >> 6] + rk16[li + k];
                    bstage[slot] = make_int2((ca[k] << 8) | ((r & 63) << 26),
                                             __float_as_int(va[k]));
                }
            }
        }
        if (blockIdx.x == 0) {  // scalar tail (E % 4): direct cursor append
            for (int e = (E & ~3) + tid; e < E; e += 512) {
                int r = rows[e];
                int p = atomicAdd(&bcursor[r >> 6], 1);
                bstage[p] = make_int2((cols[e] << 8) | ((r & 63) << 26),
                                      __float_as_int(vals[e]));
            }
        }
    } else {  // fallback: per-edge cursor atomics
        int base = blockIdx.x * EPB;
        for (int i = 0; i < 32; ++i) {
            int e = base + i * 512 + tid;
            if (e >= E) break;
            int r = rows[e];
            int p = atomicAdd(&bcursor[r >> 6], 1);
            bstage[p] = make_int2((cols[e] << 8) | ((r & 63) << 26),
                                  __float_as_int(vals[e]));
        }
    }
}

// ---------------------------------------------------------------------------
// mega: per 64-row bucket (1024 threads = 16 waves):
//  1. bucket edges -> regs; in-LDS 64-bin counting sort -> local CSR
//  2. gather: each wave accumulates 4 f-rows (f32x2 FMA, 4-wide unroll)
//  3. f -> bf16 -> swizzled LDS A-tile
//  4. GEMM via mfma_f32_16x16x32_bf16 (wave = 16x32 output tile)
//  5. bias, row-L1 via shfl + LDS float atomics, relu, residual
//     (residual reconstructed from xb * xnorm -- no x re-read), store
// ---------------------------------------------------------------------------
__global__ void __launch_bounds__(1024) mega_kernel(
    const unsigned* __restrict__ xb, const float* __restrict__ xnorm,
    int2* bstage, const int* __restrict__ bbase, const int* __restrict__ bcnt,
    const unsigned* __restrict__ Wb, const float* __restrict__ bias,
    const float* __restrict__ tsp, float* __restrict__ out, int N) {
    __shared__ char wb_raw[HD * HD * 2];     // 32 KiB bf16 W, B-layout, swz
    __shared__ char fb_raw[BROWS * HD * 2];  // 16 KiB bf16 F, A-layout, swz
    __shared__ int2 sorted[CAP];             // 16 KiB
    __shared__ int lcnt[BROWS], lbeg[BROWS], lcur[BROWS];
    __shared__ float rowsum[BROWS];

    int tid = threadIdx.x;
    int bid = blockIdx.x;
    int bb = bbase[bid];
    int ct = bcnt[bid];

    if (tid < BROWS) lcnt[tid] = 0;

    // phase 1: bucket edges -> registers
    int2 m0 = make_int2(0, 0), m1 = make_int2(0, 0);
    bool e0 = tid < ct, e1 = tid + 1024 < ct;
    if (e0) m0 = bstage[bb + tid];
    if (e1) m1 = bstage[bb + tid + 1024];
    __syncthreads();

    // phase 2: LDS histogram of local rows
    if (e0) atomicAdd(&lcnt[(unsigned)m0.x >> 26], 1);
    if (e1) atomicAdd(&lcnt[(unsigned)m1.x >> 26], 1);
    __syncthreads();

    // phase 3: wave 0 exclusive-scans the 64 counts
    if (tid < 64) {
        int c = lcnt[tid];
        int s = c;
#pragma unroll
        for (int m = 1; m < 64; m <<= 1) {
            int t2 = __shfl_up(s, m, 64);
            if (tid >= m) s += t2;
        }
        lbeg[tid] = s - c;
        lcur[tid] = s - c;
    }
    __syncthreads();

    // phase 4: scatter edges into LDS-sorted local CSR (+ stage Wb)
    if (e0) {
        int p = atomicAdd(&lcur[(unsigned)m0.x >> 26], 1);
        if (p < CAP) sorted[p] = m0; else bstage[bb + p] = m0;
    }
    if (e1) {
        int p = atomicAdd(&lcur[(unsigned)m1.x >> 26], 1);
        if (p < CAP) sorted[p] = m1; else bstage[bb + p] = m1;
    }
    {
        const float4* s4 = (const float4*)Wb;
        float4* d4 = (float4*)wb_raw;
        for (int i = tid; i < HD * HD * 2 / 16; i += 1024) d4[i] = s4[i];
    }
    __syncthreads();

    int lane = tid & 63;
    int wid = tid >> 6;
    float ts = tsp[0];
    const char* xbl = (const char*)xb + (lane << 2);

    // ---- gather: accumulate 4 f-rows (f32x2) per wave ----
    float a0[4], a1[4];
#pragma unroll
    for (int rr = 0; rr < 4; ++rr) {
        int lr = wid * 4 + rr;
        int beg = lbeg[lr], cnt = lcnt[lr];
        f32x2 pq0 = {0.f, 0.f}, pq1 = {0.f, 0.f};
        for (int jb = 0; jb < cnt; jb += 64) {
            int rem = cnt - jb;
            if (rem > 64) rem = 64;
            int2 meta = make_int2(0, 0);
            if (lane < rem) {
                int pidx = beg + jb + lane;
                meta = (pidx < CAP) ? sorted[pidx] : bstage[bb + pidx];
            }
            int j = 0;
            for (; j + 4 <= rem; j += 4) {
                int o0 = rl(meta.x, j) & META_OFF_MASK;
                int o1 = rl(meta.x, j + 1) & META_OFF_MASK;
                int o2 = rl(meta.x, j + 2) & META_OFF_MASK;
                int o3 = rl(meta.x, j + 3) & META_OFF_MASK;
                float s0 = rlf(meta.y, j), s1 = rlf(meta.y, j + 1);
                float s2 = rlf(meta.y, j + 2), s3 = rlf(meta.y, j + 3);
                unsigned u0 = *(const unsigned*)(xbl + o0);
                unsigned u1 = *(const unsigned*)(xbl + o1);
                unsigned u2 = *(const unsigned*)(xbl + o2);
                unsigned u3 = *(const unsigned*)(xbl + o3);
                pq0 += bf2f(u0) * s0;
                pq1 += bf2f(u1) * s1;
                pq0 += bf2f(u2) * s2;
                pq1 += bf2f(u3) * s3;
            }
            for (; j < rem; ++j) {
                int o0 = rl(meta.x, j) & META_OFF_MASK;
                float s0 = rlf(meta.y, j);
                unsigned u0 = *(const unsigned*)(xbl + o0);
                pq0 += bf2f(u0) * s0;
            }
        }
        a0[rr] = pq0.x + pq1.x;
        a1[rr] = pq0.y + pq1.y;
    }

    // ---- phase C: f -> bf16 swizzled LDS A-tile; init rowsum ----
#pragma unroll
    for (int rr = 0; rr < 4; ++rr) {
        int row = wid * 4 + rr;  // local row
        unsigned pk = f2bf(a0[rr]) | (f2bf(a1[rr]) << 16);
        int byte = (row * 256 + lane * 4) ^ ((row & 7) << 4);
        *(unsigned*)(fb_raw + byte) = pk;
    }
    if (tid < BROWS) rowsum[tid] = 0.f;
    __syncthreads();

    // ---- MFMA GEMM: wave -> 16-row x 32-col output tile ----
    int rt = wid >> 2;        // row-tile 0..3
    int ct0 = (wid & 3) * 2;  // first col-tile (of 8)
    int c = lane & 15;
    int kg = lane >> 4;
    int arow = rt * 16 + c;
    int bcol0 = ct0 * 16 + c;
    int bcol1 = bcol0 + 16;
    f32x4 acc0 = {0.f, 0.f, 0.f, 0.f}, acc1 = {0.f, 0.f, 0.f, 0.f};
#pragma unroll
    for (int kk = 0; kk < 4; ++kk) {
        int ka = kg * 16 + kk * 64;  // byte offset of this lane's k-chunk
        short8v af = *(const short8v*)(fb_raw +
                                       ((arow * 256 + ka) ^ ((arow & 7) << 4)));
        short8v bf0 = *(const short8v*)(wb_raw +
                                        ((bcol0 * 256 + ka) ^ ((bcol0 & 7) << 4)));
        short8v bf1 = *(const short8v*)(wb_raw +
                                        ((bcol1 * 256 + ka) ^ ((bcol1 & 7) << 4)));
        acc0 = __builtin_amdgcn_mfma_f32_16x16x32_bf16(af, bf0, acc0, 0, 0, 0);
        acc1 = __builtin_amdgcn_mfma_f32_16x16x32_bf16(af, bf1, acc1, 0, 0, 0);
    }

    // ---- epilogue: bias, row-L1 reduce, normalize, relu, residual ----
    float bias0 = bias[bcol0];
    float bias1 = bias[bcol1];
    float g0r[4], g1r[4];
#pragma unroll
    for (int r = 0; r < 4; ++r) {
        float v0 = acc0[r] + bias0;
        float v1 = acc1[r] + bias1;
        g0r[r] = v0;
        g1r[r] = v1;
        float s = fabsf(v0) + fabsf(v1);
        s += __shfl_xor(s, 1, 64);
        s += __shfl_xor(s, 2, 64);
        s += __shfl_xor(s, 4, 64);
        s += __shfl_xor(s, 8, 64);
        if (c == 0) atomicAdd(&rowsum[rt * 16 + kg * 4 + r], s);
    }
    __syncthreads();
#pragma unroll
    for (int r = 0; r < 4; ++r) {
        int lrow = rt * 16 + kg * 4 + r;
        int row = bid * BROWS + lrow;
        if (row < N) {
            float rn = 1.0f / fmaxf(rowsum[lrow], 1e-12f);
            float G0 = fmaxf(g0r[r] * rn, 0.f);
            float G1 = fmaxf(g1r[r] * rn, 0.f);
            // residual reconstruction: x = bf16(x * (1/norm)) * norm
            float nm = xnorm[row];
            unsigned u0 = xb[(size_t)row * 64 + ct0 * 8 + (c >> 1)];
            unsigned u1 = xb[(size_t)row * 64 + ct0 * 8 + 8 + (c >> 1)];
            unsigned h0 = (c & 1) ? (u0 & 0xffff0000u) : (u0 << 16);
            unsigned h1 = (c & 1) ? (u1 & 0xffff0000u) : (u1 << 16);
            float x0 = __uint_as_float(h0) * nm;
            float x1 = __uint_as_float(h1) * nm;
            out[(size_t)row * HD + bcol0] = fmaf(ts, G0, x0);
            out[(size_t)row * HD + bcol1] = fmaf(ts, G1, x1);
        }
    }
}

extern "C" void kernel_launch(void* const* d_in, const int* in_sizes, int n_in,
                              void* d_out, int out_size, void* d_ws,
                              size_t ws_size, hipStream_t stream) {
    const float* x = (const float*)d_in[0];
    const int* Ar = (const int*)d_in[1];
    const int* Ac = (const int*)d_in[2];
    const float* Av = (const float*)d_in[3];
    const float* W = (const float*)d_in[4];
    const float* b = (const float*)d_in[5];
    const float* ts = (const float*)d_in[6];

    int N = in_sizes[0] / HD;
    int E = in_sizes[1];
    float* out = (float*)d_out;

    int NB = (N + BROWS - 1) / BROWS;

    char* ws = (char*)d_ws;
    size_t o = 0;
    auto take = [&](size_t bytes) {
        void* p = ws + o;
        o += (bytes + 511) & ~(size_t)511;
        return p;
    };
    int* bcnt = (int*)take((size_t)NB * 4);
    int* bbase = (int*)take((size_t)NB * 4);
    int* bcursor = (int*)take((size_t)NB * 4);
    float* xnorm = (float*)take((size_t)N * 4);
    unsigned* Wb = (unsigned*)take((size_t)HD * HD * 2);
    unsigned* xb = (unsigned*)take((size_t)N * 64 * 4);
    int2* bstage = (int2*)take((size_t)E * 8);

    int PB = (N + 3) / 4;
    int EB = (E + EPB - 1) / EPB;
    prep_kernel<<<PB + 33, 256, 0, stream>>>(x, xb, xnorm, W, Wb, bcnt, N, PB,
                                             NB);
    count_kernel<<<EB, 512, 0, stream>>>(Ar, bcnt, E, NB);
    bscan_kernel<<<1, 1024, 0, stream>>>(bcnt, bbase, bcursor, NB);
    scatter_kernel<<<EB, 512, 0, stream>>>(Ar, Ac, Av, bcursor, bstage, E, NB);
    mega_kernel<<<NB, 1024, 0, stream>>>(xb, xnorm, bstage, bbase, bcnt, Wb, b,
                                         ts, out, N);
}